// Round 3
// baseline (512.628 us; speedup 1.0000x reference)
//
#include <hip/hip_runtime.h>

#define BS   8
#define NCH  7
#define PX   409600      // 640*640
#define NBIN 65536
#define NBLK 400         // blocks per sample in the big passes: 400*256*4 = PX
#define EPSF 1e-6f

__device__ __forceinline__ float sigf(float x) {
    return 1.0f / (1.0f + __expf(-x));
}

__device__ __forceinline__ unsigned wred_u(unsigned v) {
    #pragma unroll
    for (int o = 32; o; o >>= 1) v += __shfl_down(v, o);
    return v;
}

__device__ __forceinline__ float wred_f(float v) {
    #pragma unroll
    for (int o = 32; o; o >>= 1) v += __shfl_down(v, o);
    return v;
}

// =====================================================================================
// K1: single cold pass. One float4-group (4 px) per thread, straight-line.
//  - global-atomic histogram of negatives of pred_n (top-16-bit bins), n_pos
//  - 18 thr-independent L_s partial sums -> part[b][3+j][bx] (plain stores)
// =====================================================================================
__global__ __launch_bounds__(256, 4) void k_main(const float* __restrict__ preds,
                                                 const int* __restrict__ labels,
                                                 const int* __restrict__ mask,
                                                 unsigned* __restrict__ hist1,
                                                 unsigned* __restrict__ n_pos,
                                                 float* __restrict__ part) {
    int b = blockIdx.y;
    int bx = blockIdx.x;
    int px = (bx * 256 + threadIdx.x) * 4;
    const float* pr = preds + (size_t)b * NCH * PX;
    const int*   lb = labels + (size_t)b * NCH * PX;
    const int*   mk = mask + (size_t)b * PX;

    // ---- issue ALL loads up front (14 x 16B) ----
    float4 p6 = *(const float4*)(pr + 6 * PX + px);
    int4   m4 = *(const int4*)(mk + px);
    float4 pc[6];
    int4   lc[6];
    #pragma unroll
    for (int c = 0; c < 6; c++) {
        pc[c] = *(const float4*)(pr + c * PX + px);
        lc[c] = *(const int4*)(lb + c * PX + px);
    }

    float mm[4]  = {(float)m4.x, (float)m4.y, (float)m4.z, (float)m4.w};
    float p6a[4] = {p6.x, p6.y, p6.z, p6.w};
    float W[4];
    unsigned pos_cnt = 0, zero_cnt = 0;
    unsigned* hb = hist1 + (size_t)b * NBIN;

    #pragma unroll
    for (int u = 0; u < 4; u++) {
        float pn = sigf(p6a[u]) * mm[u];
        if (pn >= 0.5f) {
            pos_cnt++; W[u] = 1.0f;
        } else {
            W[u] = 0.0f;
            unsigned bits = __float_as_uint(pn);
            if (bits == 0u) zero_cnt++;
            else            atomicAdd(&hb[bits >> 16], 1u);   // fire-and-forget
        }
    }

    float acc[18];
    #pragma unroll
    for (int j = 0; j < 18; j++) acc[j] = 0.f;
    #pragma unroll
    for (int c = 0; c < 6; c++) {
        float pcs[4] = {pc[c].x, pc[c].y, pc[c].z, pc[c].w};
        float lcs[4] = {(float)lc[c].x, (float)lc[c].y, (float)lc[c].z, (float)lc[c].w};
        #pragma unroll
        for (int u = 0; u < 4; u++) {
            float s = sigf(pcs[u]);
            float l = lcs[u];
            acc[c]      += s * l * W[u];
            acc[6 + c]  += s * s * W[u];
            acc[12 + c] += l * W[u];
        }
    }

    // ---- block reduction ----
    int lane = threadIdx.x & 63, wid = threadIdx.x >> 6;
    __shared__ float red[4][18];
    __shared__ unsigned ws2[2][4];
    #pragma unroll
    for (int j = 0; j < 18; j++) {
        float v = wred_f(acc[j]);
        if (lane == 0) red[wid][j] = v;
    }
    unsigned pv = wred_u(pos_cnt), zv = wred_u(zero_cnt);
    if (lane == 0) { ws2[0][wid] = pv; ws2[1][wid] = zv; }
    __syncthreads();
    if (threadIdx.x < 18) {
        float tot = red[0][threadIdx.x] + red[1][threadIdx.x] +
                    red[2][threadIdx.x] + red[3][threadIdx.x];
        part[((size_t)b * 21 + 3 + threadIdx.x) * NBLK + bx] = tot;   // plain store
    }
    if (threadIdx.x == 0) {
        unsigned pt = ws2[0][0] + ws2[0][1] + ws2[0][2] + ws2[0][3];
        unsigned zt = ws2[1][0] + ws2[1][1] + ws2[1][2] + ws2[1][3];
        if (pt) atomicAdd(&n_pos[b], pt);
        if (zt) atomicAdd(&hb[0], zt);       // zeros -> bin 0
    }
}

// =====================================================================================
// select over 65536 bins, 256 threads. Chunk sums computed on the fly:
// wave w sums chunks [w*64, w*64+64) with coalesced uint4 reads + shuffle reduce.
// Finds bin s.t. count(bins >= bin) >= k, strictly < k above; rank within bin.
// =====================================================================================
__device__ void select2(const unsigned* __restrict__ bins, unsigned k,
                        unsigned* out_bin, unsigned* out_rank) {
    __shared__ unsigned cs[256];
    __shared__ unsigned sel_c, sel_r;
    int t = threadIdx.x, lane = t & 63, wid = t >> 6;

    for (int c = wid * 64; c < wid * 64 + 64; c++) {
        uint4 v = *((const uint4*)(bins + c * 256) + lane);
        unsigned s = wred_u(v.x + v.y + v.z + v.w);
        if (lane == 0) cs[c] = s;
    }
    __syncthreads();
    #pragma unroll
    for (int off = 1; off < 256; off <<= 1) {
        unsigned v = cs[t];
        unsigned a = (t + off < 256) ? cs[t + off] : 0u;
        __syncthreads();
        cs[t] = v + a;
        __syncthreads();
    }
    {
        unsigned sfx  = cs[t];
        unsigned sfx1 = (t < 255) ? cs[t + 1] : 0u;
        if (sfx >= k && sfx1 < k) { sel_c = (unsigned)t; sel_r = k - sfx1; }
    }
    __syncthreads();
    unsigned chunk = sel_c, krem = sel_r;
    cs[t] = bins[chunk * 256 + t];
    __syncthreads();
    #pragma unroll
    for (int off = 1; off < 256; off <<= 1) {
        unsigned v = cs[t];
        unsigned a = (t + off < 256) ? cs[t + off] : 0u;
        __syncthreads();
        cs[t] = v + a;
        __syncthreads();
    }
    {
        unsigned sfx  = cs[t];
        unsigned sfx1 = (t < 255) ? cs[t + 1] : 0u;
        if (sfx >= krem && sfx1 < krem) {
            *out_bin  = chunk * 256 + (unsigned)t;
            *out_rank = krem - sfx1;
        }
    }
    __syncthreads();
}

// ---------------- K2: find top-16-bit bin of the k-th largest negative --------------
__global__ __launch_bounds__(256) void k_find_hi(const unsigned* __restrict__ hist1,
                                                 const unsigned* __restrict__ n_pos,
                                                 unsigned* __restrict__ hi_bin,
                                                 unsigned* __restrict__ rankv,
                                                 unsigned* __restrict__ activev,
                                                 float* __restrict__ thr) {
    int b = blockIdx.x;
    unsigned np_ = n_pos[b];
    unsigned k = np_ * 3u;
    unsigned nneg = (unsigned)PX - np_;
    if (!(nneg > k && k > 0u)) {
        if (threadIdx.x == 0) { activev[b] = 0u; thr[b] = -1.0f; }  // M = 1 everywhere
        return;
    }
    __shared__ unsigned rb, rr;
    select2(hist1 + (size_t)b * NBIN, k, &rb, &rr);
    if (threadIdx.x == 0) {
        activev[b] = 1u;
        hi_bin[b] = rb;
        rankv[b] = rr;
        // bin 0 holds exactly-0 values; thr=0 includes them all, contributions are 0.
        if (rb == 0u) thr[b] = 0.0f;
    }
}

// ---------------- K3: refine — low-16-bit histogram within selected hi bin ----------
__global__ __launch_bounds__(256) void k_refine(const float* __restrict__ preds,
                                                const int* __restrict__ mask,
                                                const unsigned* __restrict__ hi_bin,
                                                const unsigned* __restrict__ activev,
                                                unsigned* __restrict__ hist2) {
    int b = blockIdx.y;
    if (!activev[b]) return;
    unsigned hi = hi_bin[b];
    if (hi == 0u) return;   // thr already resolved to 0.0f
    int px = (blockIdx.x * 256 + threadIdx.x) * 4;
    const float* pr = preds + ((size_t)b * NCH + 6) * PX;
    const int* mk = mask + (size_t)b * PX;
    unsigned* h2 = hist2 + (size_t)b * NBIN;
    float4 p6 = *(const float4*)(pr + px);
    int4   m4 = *(const int4*)(mk + px);
    float p6a[4] = {p6.x, p6.y, p6.z, p6.w};
    float mm[4]  = {(float)m4.x, (float)m4.y, (float)m4.z, (float)m4.w};
    #pragma unroll
    for (int u = 0; u < 4; u++) {
        float pn = sigf(p6a[u]) * mm[u];
        if (pn < 0.5f) {
            unsigned bits = __float_as_uint(pn);
            if ((bits >> 16) == hi) atomicAdd(&h2[bits & 0xFFFFu], 1u);
        }
    }
}

// ---------------- K4: resolve exact threshold bits ----------------------------------
__global__ __launch_bounds__(256) void k_find_lo(const unsigned* __restrict__ hist2,
                                                 const unsigned* __restrict__ hi_bin,
                                                 const unsigned* __restrict__ rankv,
                                                 const unsigned* __restrict__ activev,
                                                 float* __restrict__ thr) {
    int b = blockIdx.x;
    if (!activev[b]) return;
    unsigned hi = hi_bin[b];
    if (hi == 0u) return;
    __shared__ unsigned rb, rr;
    select2(hist2 + (size_t)b * NBIN, rankv[b], &rb, &rr);
    if (threadIdx.x == 0) thr[b] = __uint_as_float((hi << 16) | rb);
}

// ---------------- K5: the 3 thr-dependent L_c sums (ch6+mask+labels6, L3-hot) -------
__global__ __launch_bounds__(256, 4) void k_lc(const float* __restrict__ preds,
                                               const int* __restrict__ labels,
                                               const int* __restrict__ mask,
                                               const float* __restrict__ thr,
                                               float* __restrict__ part) {
    int b = blockIdx.y;
    int bx = blockIdx.x;
    int px = (bx * 256 + threadIdx.x) * 4;
    const float* pr = preds + ((size_t)b * NCH + 6) * PX;
    const int*   lb = labels + ((size_t)b * NCH + 6) * PX;
    const int*   mk = mask + (size_t)b * PX;
    float thr_b = thr[b];

    float4 p6 = *(const float4*)(pr + px);
    int4   l4 = *(const int4*)(lb + px);
    int4   m4 = *(const int4*)(mk + px);
    float p6a[4] = {p6.x, p6.y, p6.z, p6.w};
    float la[4]  = {(float)l4.x, (float)l4.y, (float)l4.z, (float)l4.w};
    float mm[4]  = {(float)m4.x, (float)m4.y, (float)m4.z, (float)m4.w};

    float a0 = 0.f, a1 = 0.f, a2 = 0.f;
    #pragma unroll
    for (int u = 0; u < 4; u++) {
        float pn = sigf(p6a[u]) * mm[u];
        float Mi = (pn >= thr_b) ? 1.0f : 0.0f;
        float ln = la[u] * mm[u];
        a0 += pn * ln * Mi;
        a1 += pn * pn * Mi;
        a2 += ln * Mi;
    }
    __shared__ float red[4][3];
    int lane = threadIdx.x & 63, wid = threadIdx.x >> 6;
    float v0 = wred_f(a0), v1 = wred_f(a1), v2 = wred_f(a2);
    if (lane == 0) { red[wid][0] = v0; red[wid][1] = v1; red[wid][2] = v2; }
    __syncthreads();
    if (threadIdx.x < 3) {
        float tot = red[0][threadIdx.x] + red[1][threadIdx.x] +
                    red[2][threadIdx.x] + red[3][threadIdx.x];
        part[((size_t)b * 21 + threadIdx.x) * NBLK + bx] = tot;   // plain store
    }
}

// ---------------- K6: reduce partials (168 rows x 400 cols) + dice + means ----------
__global__ __launch_bounds__(256) void k_final(const float* __restrict__ part,
                                               float* __restrict__ out) {
    __shared__ float fr[BS * 21];
    int lane = threadIdx.x & 63, wid = threadIdx.x >> 6;
    for (int r = wid; r < BS * 21; r += 4) {
        const float* row = part + (size_t)r * NBLK;
        float s = 0.f;
        for (int c = lane; c < NBLK; c += 64) s += row[c];   // coalesced
        s = wred_f(s);
        if (lane == 0) fr[r] = s;
    }
    __syncthreads();
    if (threadIdx.x == 0) {
        float Lc = 0.f, Ls = 0.f;
        #pragma unroll
        for (int b = 0; b < BS; b++) {
            const float* s = fr + b * 21;
            Lc += 1.0f - (2.0f * s[0]) / (s[1] + s[2] + EPSF);
            float acc = 0.f;
            #pragma unroll
            for (int c = 0; c < 6; c++)
                acc += (2.0f * s[3 + c]) / (s[9 + c] + s[15 + c] + EPSF);
            Ls += 1.0f - acc * (1.0f / 6.0f);
        }
        float lc_m = Lc * (1.0f / (float)BS);
        float ls_m = Ls * (1.0f / (float)BS);
        out[0] = lc_m;
        out[1] = ls_m;
        out[2] = 0.7f * lc_m + 0.3f * ls_m;
    }
}

extern "C" void kernel_launch(void* const* d_in, const int* in_sizes, int n_in,
                              void* d_out, int out_size, void* d_ws, size_t ws_size,
                              hipStream_t stream) {
    const float* preds = (const float*)d_in[0];
    const int* labels  = (const int*)d_in[1];
    const int* mask    = (const int*)d_in[2];
    float* out = (float*)d_out;

    // workspace layout (u32/f32 words)
    unsigned* hist1   = (unsigned*)d_ws;              // BS * NBIN
    unsigned* hist2   = hist1 + (size_t)BS * NBIN;    // BS * NBIN
    unsigned* n_pos   = hist2 + (size_t)BS * NBIN;    // BS   (contiguous w/ hists for one memset)
    unsigned* hi_bin  = n_pos + BS;                   // BS
    unsigned* rankv   = hi_bin + BS;                  // BS
    unsigned* activev = rankv + BS;                   // BS
    float*    thr     = (float*)(activev + BS);       // BS
    float*    part    = thr + BS;                     // BS * 21 * NBLK (plain stores, no zeroing)

    size_t zero_words = (size_t)2 * BS * NBIN + BS;   // hist1 + hist2 + n_pos
    hipMemsetAsync(d_ws, 0, zero_words * sizeof(unsigned), stream);

    hipLaunchKernelGGL(k_main, dim3(NBLK, BS), dim3(256), 0, stream,
                       preds, labels, mask, hist1, n_pos, part);

    hipLaunchKernelGGL(k_find_hi, dim3(BS), dim3(256), 0, stream,
                       hist1, n_pos, hi_bin, rankv, activev, thr);

    hipLaunchKernelGGL(k_refine, dim3(NBLK, BS), dim3(256), 0, stream,
                       preds, mask, hi_bin, activev, hist2);

    hipLaunchKernelGGL(k_find_lo, dim3(BS), dim3(256), 0, stream,
                       hist2, hi_bin, rankv, activev, thr);

    hipLaunchKernelGGL(k_lc, dim3(NBLK, BS), dim3(256), 0, stream,
                       preds, labels, mask, thr, part);

    hipLaunchKernelGGL(k_final, dim3(1), dim3(256), 0, stream, part, out);
}

// Round 4
// 330.731 us; speedup vs baseline: 1.5500x; 1.5500x over previous
//
#include <hip/hip_runtime.h>

#define BS   8
#define NCH  7
#define PX   409600      // 640*640
#define NBIN 65536
#define NBLK 400         // px-blocks per sample in k_sums: 400*256*4 = PX
#define WIN_LO 0x3000u   // LDS histogram window over top-16 bits: [0x3000, 0x4000)
#define WIN_SZ 4096
#define EPSF 1e-6f

__device__ __forceinline__ float sigf(float x) {
    return 1.0f / (1.0f + __expf(-x));
}

__device__ __forceinline__ unsigned wred_u(unsigned v) {
    #pragma unroll
    for (int o = 32; o; o >>= 1) v += __shfl_down(v, o);
    return v;
}

__device__ __forceinline__ float wred_f(float v) {
    #pragma unroll
    for (int o = 32; o; o >>= 1) v += __shfl_down(v, o);
    return v;
}

// =====================================================================================
// A: ch6 + mask pass (26 MB). LDS window histogram (NO scattered global atomics in the
// loop — R3 showed those collapse the memory pipe), W byte-map, n_pos.
// =====================================================================================
__global__ __launch_bounds__(256) void k_prep(const float* __restrict__ preds,
                                              const int* __restrict__ mask,
                                              unsigned* __restrict__ hist1,
                                              unsigned* __restrict__ n_pos,
                                              unsigned char* __restrict__ wmask) {
    int b = blockIdx.y;
    const float* pr = preds + ((size_t)b * NCH + 6) * PX;
    const int*   mk = mask + (size_t)b * PX;
    unsigned char* wm = wmask + (size_t)b * PX;

    __shared__ unsigned lh[WIN_SZ];
    for (int j = threadIdx.x; j < WIN_SZ; j += 256) lh[j] = 0u;
    __syncthreads();

    unsigned pos_cnt = 0, zero_cnt = 0;
    for (int g = blockIdx.x * 256 + threadIdx.x; g < PX / 4; g += gridDim.x * 256) {
        int px = g * 4;
        float4 p6 = *(const float4*)(pr + px);
        int4   m4 = *(const int4*)(mk + px);
        float p6a[4] = {p6.x, p6.y, p6.z, p6.w};
        float mm[4]  = {(float)m4.x, (float)m4.y, (float)m4.z, (float)m4.w};
        unsigned char w[4];
        #pragma unroll
        for (int u = 0; u < 4; u++) {
            float pn = sigf(p6a[u]) * mm[u];
            if (pn >= 0.5f) {
                pos_cnt++; w[u] = 1;
            } else {
                w[u] = 0;
                unsigned bits = __float_as_uint(pn);
                if (bits == 0u) {
                    zero_cnt++;
                } else {
                    unsigned hb = bits >> 16;
                    if (hb - WIN_LO < WIN_SZ)
                        atomicAdd(&lh[hb - WIN_LO], 1u);          // LDS only
                    else
                        atomicAdd(&hist1[(size_t)b * NBIN + hb], 1u);  // rare fallback
                }
            }
        }
        *(uchar4*)(wm + px) = make_uchar4(w[0], w[1], w[2], w[3]);
    }
    __syncthreads();

    // lane-contiguous flush (proven R2 pattern)
    for (int j = threadIdx.x; j < WIN_SZ; j += 256) {
        unsigned c = lh[j];
        if (c) atomicAdd(&hist1[(size_t)b * NBIN + WIN_LO + j], c);
    }

    __shared__ unsigned ws2[2][4];
    unsigned pv = wred_u(pos_cnt), zv = wred_u(zero_cnt);
    int lane = threadIdx.x & 63, wid = threadIdx.x >> 6;
    if (lane == 0) { ws2[0][wid] = pv; ws2[1][wid] = zv; }
    __syncthreads();
    if (threadIdx.x == 0) {
        unsigned pt = ws2[0][0] + ws2[0][1] + ws2[0][2] + ws2[0][3];
        unsigned zt = ws2[1][0] + ws2[1][1] + ws2[1][2] + ws2[1][3];
        if (pt) atomicAdd(&n_pos[b], pt);
        if (zt) atomicAdd(&hist1[(size_t)b * NBIN], zt);   // exact zeros -> bin 0
    }
}

// =====================================================================================
// select over 65536 bins with 256 threads; chunk sums computed on the fly (coalesced).
// =====================================================================================
__device__ void select2(const unsigned* __restrict__ bins, unsigned k,
                        unsigned* out_bin, unsigned* out_rank) {
    __shared__ unsigned cs[256];
    __shared__ unsigned sel_c, sel_r;
    int t = threadIdx.x, lane = t & 63, wid = t >> 6;

    for (int c = wid * 64; c < wid * 64 + 64; c++) {
        uint4 v = *((const uint4*)(bins + c * 256) + lane);
        unsigned s = wred_u(v.x + v.y + v.z + v.w);
        if (lane == 0) cs[c] = s;
    }
    __syncthreads();
    #pragma unroll
    for (int off = 1; off < 256; off <<= 1) {
        unsigned v = cs[t];
        unsigned a = (t + off < 256) ? cs[t + off] : 0u;
        __syncthreads();
        cs[t] = v + a;
        __syncthreads();
    }
    {
        unsigned sfx  = cs[t];
        unsigned sfx1 = (t < 255) ? cs[t + 1] : 0u;
        if (sfx >= k && sfx1 < k) { sel_c = (unsigned)t; sel_r = k - sfx1; }
    }
    __syncthreads();
    unsigned chunk = sel_c, krem = sel_r;
    cs[t] = bins[chunk * 256 + t];
    __syncthreads();
    #pragma unroll
    for (int off = 1; off < 256; off <<= 1) {
        unsigned v = cs[t];
        unsigned a = (t + off < 256) ? cs[t + off] : 0u;
        __syncthreads();
        cs[t] = v + a;
        __syncthreads();
    }
    {
        unsigned sfx  = cs[t];
        unsigned sfx1 = (t < 255) ? cs[t + 1] : 0u;
        if (sfx >= krem && sfx1 < krem) {
            *out_bin  = chunk * 256 + (unsigned)t;
            *out_rank = krem - sfx1;
        }
    }
    __syncthreads();
}

// =====================================================================================
// fused selection: find hi bin; hi==0 -> thr=0 (zeros contribute 0 to every L_c sum,
// exactly equivalent). hi!=0 (not taken for this data, kept correct): refine in-kernel.
// =====================================================================================
__global__ __launch_bounds__(256) void k_select(const float* __restrict__ preds,
                                                const int* __restrict__ mask,
                                                const unsigned* __restrict__ hist1,
                                                unsigned* __restrict__ hist2,
                                                const unsigned* __restrict__ n_pos,
                                                float* __restrict__ thr) {
    int b = blockIdx.x;
    unsigned np_ = n_pos[b];
    unsigned k = np_ * 3u;
    unsigned nneg = (unsigned)PX - np_;
    if (!(nneg > k && k > 0u)) {
        if (threadIdx.x == 0) thr[b] = -1.0f;   // inactive: M = 1 everywhere
        return;
    }
    __shared__ unsigned rb, rr;
    select2(hist1 + (size_t)b * NBIN, k, &rb, &rr);
    if (rb == 0u) {
        if (threadIdx.x == 0) thr[b] = 0.0f;
        return;
    }
    // ---- slow path (block-uniform branch; never taken for this data) ----
    unsigned hi = rb, krem = rr;
    unsigned* h2 = hist2 + (size_t)b * NBIN;
    for (int j = threadIdx.x; j < NBIN; j += 256) h2[j] = 0u;   // lazy zero (ws poisoned)
    __threadfence();
    __syncthreads();
    const float* pr = preds + ((size_t)b * NCH + 6) * PX;
    const int*   mk = mask + (size_t)b * PX;
    for (int g = threadIdx.x; g < PX / 4; g += 256) {
        int px = g * 4;
        float4 p6 = *(const float4*)(pr + px);
        int4   m4 = *(const int4*)(mk + px);
        float p6a[4] = {p6.x, p6.y, p6.z, p6.w};
        float mm[4]  = {(float)m4.x, (float)m4.y, (float)m4.z, (float)m4.w};
        #pragma unroll
        for (int u = 0; u < 4; u++) {
            float pn = sigf(p6a[u]) * mm[u];
            if (pn < 0.5f) {
                unsigned bits = __float_as_uint(pn);
                if ((bits >> 16) == hi) atomicAdd(&h2[bits & 0xFFFFu], 1u);
            }
        }
    }
    __threadfence();
    __syncthreads();
    __shared__ unsigned rb2, rr2;
    select2(h2, krem, &rb2, &rr2);
    if (threadIdx.x == 0) thr[b] = __uint_as_float((hi << 16) | rb2);
}

// =====================================================================================
// B: grid (NBLK, 7, BS). One channel per block -> 3 load streams/thread, straight-line.
//   ch 0..5 : sn, sp, sl gated by W byte
//   ch 6    : a0, a1, a2 gated by thr (ch6/mask re-read is L3-hot from k_prep)
// partial sums -> part[((b*7+ch)*3+j)*NBLK + bx] (plain stores)
// =====================================================================================
__global__ __launch_bounds__(256) void k_sums(const float* __restrict__ preds,
                                              const int* __restrict__ labels,
                                              const int* __restrict__ mask,
                                              const unsigned char* __restrict__ wmask,
                                              const float* __restrict__ thr,
                                              float* __restrict__ part) {
    int b = blockIdx.z, ch = blockIdx.y, bx = blockIdx.x;
    int px = (bx * 256 + threadIdx.x) * 4;
    float s0 = 0.f, s1 = 0.f, s2 = 0.f;

    if (ch < 6) {
        const float* pr = preds + ((size_t)b * NCH + ch) * PX;
        const int*   lb = labels + ((size_t)b * NCH + ch) * PX;
        float4 p4 = *(const float4*)(pr + px);
        int4   l4 = *(const int4*)(lb + px);
        uchar4 w4 = *(const uchar4*)(wmask + (size_t)b * PX + px);
        float ps[4] = {p4.x, p4.y, p4.z, p4.w};
        float ls[4] = {(float)l4.x, (float)l4.y, (float)l4.z, (float)l4.w};
        float ws[4] = {(float)w4.x, (float)w4.y, (float)w4.z, (float)w4.w};
        #pragma unroll
        for (int u = 0; u < 4; u++) {
            float s = sigf(ps[u]);
            float l = ls[u];
            float W = ws[u];
            s0 += s * l * W;
            s1 += s * s * W;
            s2 += l * W;          // l*l == l (labels are 0/1)
        }
    } else {
        const float* pr = preds + ((size_t)b * NCH + 6) * PX;
        const int*   lb = labels + ((size_t)b * NCH + 6) * PX;
        const int*   mk = mask + (size_t)b * PX;
        float t = thr[b];
        float4 p4 = *(const float4*)(pr + px);
        int4   l4 = *(const int4*)(lb + px);
        int4   m4 = *(const int4*)(mk + px);
        float ps[4] = {p4.x, p4.y, p4.z, p4.w};
        float ls[4] = {(float)l4.x, (float)l4.y, (float)l4.z, (float)l4.w};
        float mm[4] = {(float)m4.x, (float)m4.y, (float)m4.z, (float)m4.w};
        #pragma unroll
        for (int u = 0; u < 4; u++) {
            float pn = sigf(ps[u]) * mm[u];
            float Mi = (pn >= t) ? 1.0f : 0.0f;
            float ln = ls[u] * mm[u];
            s0 += pn * ln * Mi;
            s1 += pn * pn * Mi;
            s2 += ln * Mi;        // ln*ln == ln
        }
    }

    __shared__ float red[4][3];
    int lane = threadIdx.x & 63, wid = threadIdx.x >> 6;
    float v0 = wred_f(s0), v1 = wred_f(s1), v2 = wred_f(s2);
    if (lane == 0) { red[wid][0] = v0; red[wid][1] = v1; red[wid][2] = v2; }
    __syncthreads();
    if (threadIdx.x < 3) {
        float tot = red[0][threadIdx.x] + red[1][threadIdx.x] +
                    red[2][threadIdx.x] + red[3][threadIdx.x];
        part[(((size_t)b * 7 + ch) * 3 + threadIdx.x) * NBLK + bx] = tot;
    }
}

// ---------------- final: reduce 168 rows x NBLK partials + dice + means --------------
__global__ __launch_bounds__(256) void k_final(const float* __restrict__ part,
                                               float* __restrict__ out) {
    __shared__ float fr[BS * 21];
    int lane = threadIdx.x & 63, wid = threadIdx.x >> 6;
    for (int r = wid; r < BS * 21; r += 4) {
        const float* row = part + (size_t)r * NBLK;
        float s = 0.f;
        for (int c = lane; c < NBLK; c += 64) s += row[c];   // coalesced
        s = wred_f(s);
        if (lane == 0) fr[r] = s;
    }
    __syncthreads();
    if (threadIdx.x == 0) {
        float Lc = 0.f, Ls = 0.f;
        #pragma unroll
        for (int b = 0; b < BS; b++) {
            const float* s6 = fr + (b * 7 + 6) * 3;
            Lc += 1.0f - (2.0f * s6[0]) / (s6[1] + s6[2] + EPSF);
            float acc = 0.f;
            #pragma unroll
            for (int c = 0; c < 6; c++) {
                const float* sc = fr + (b * 7 + c) * 3;
                acc += (2.0f * sc[0]) / (sc[1] + sc[2] + EPSF);
            }
            Ls += 1.0f - acc * (1.0f / 6.0f);
        }
        float lc_m = Lc * (1.0f / (float)BS);
        float ls_m = Ls * (1.0f / (float)BS);
        out[0] = lc_m;
        out[1] = ls_m;
        out[2] = 0.7f * lc_m + 0.3f * ls_m;
    }
}

extern "C" void kernel_launch(void* const* d_in, const int* in_sizes, int n_in,
                              void* d_out, int out_size, void* d_ws, size_t ws_size,
                              hipStream_t stream) {
    const float* preds = (const float*)d_in[0];
    const int* labels  = (const int*)d_in[1];
    const int* mask    = (const int*)d_in[2];
    float* out = (float*)d_out;

    // workspace layout
    unsigned* hist1 = (unsigned*)d_ws;                      // BS*NBIN   (zeroed)
    unsigned* n_pos = hist1 + (size_t)BS * NBIN;            // BS        (zeroed)
    unsigned* hist2 = n_pos + BS;                           // BS*NBIN   (lazy-zeroed)
    float*    thr   = (float*)(hist2 + (size_t)BS * NBIN);  // BS
    unsigned char* wmask = (unsigned char*)(thr + BS);      // BS*PX bytes
    float*    part  = (float*)(wmask + (size_t)BS * PX);    // BS*21*NBLK

    size_t zero_words = (size_t)BS * NBIN + BS;             // hist1 + n_pos only
    hipMemsetAsync(d_ws, 0, zero_words * sizeof(unsigned), stream);

    hipLaunchKernelGGL(k_prep, dim3(100, BS), dim3(256), 0, stream,
                       preds, mask, hist1, n_pos, wmask);

    hipLaunchKernelGGL(k_select, dim3(BS), dim3(256), 0, stream,
                       preds, mask, hist1, hist2, n_pos, thr);

    hipLaunchKernelGGL(k_sums, dim3(NBLK, 7, BS), dim3(256), 0, stream,
                       preds, labels, mask, wmask, thr, part);

    hipLaunchKernelGGL(k_final, dim3(1), dim3(256), 0, stream, part, out);
}

// Round 5
// 256.429 us; speedup vs baseline: 1.9991x; 1.2898x over previous
//
#include <hip/hip_runtime.h>

#define BS   8
#define NCH  7
#define PX   409600      // 640*640
#define PBLK 200         // blocks per sample: 200*256*8 = PX
#define EPSF 1e-6f

__device__ __forceinline__ float sigf(float x) {
    return 1.0f / (1.0f + __expf(-x));
}

__device__ __forceinline__ unsigned wred_u(unsigned v) {
    #pragma unroll
    for (int o = 32; o; o >>= 1) v += __shfl_down(v, o);
    return v;
}

__device__ __forceinline__ float wred_f(float v) {
    #pragma unroll
    for (int o = 32; o; o >>= 1) v += __shfl_down(v, o);
    return v;
}

// sums layout: sums[(b*7+ch)*3 + j]; ch 0..5 = L_s (sn,sp,sl), ch 6 = L_c (a0,a1,a2)

// =====================================================================================
// K1: ch6 + labels6 + mask (39 MB). 8 px/thread straight-line, 6 load streams.
//  - n_pos, n_nonzero_neg counters
//  - W byte map (8B store)
//  - L_c sums computed with M == 1 (exact fast path; k_fix repairs if ever wrong)
//  finish: 5 atomicAdds per block (R2-proven pattern, ~200 per address)
// =====================================================================================
__global__ __launch_bounds__(256, 4) void k_prep(const float* __restrict__ preds,
                                                 const int* __restrict__ labels,
                                                 const int* __restrict__ mask,
                                                 unsigned* __restrict__ n_pos,
                                                 unsigned* __restrict__ n_nz,
                                                 unsigned char* __restrict__ wmask,
                                                 float* __restrict__ sums) {
    int b = blockIdx.y;
    int base = (blockIdx.x * 256 + threadIdx.x) * 8;
    const float* pr = preds + ((size_t)b * NCH + 6) * PX;
    const int*   lb = labels + ((size_t)b * NCH + 6) * PX;
    const int*   mk = mask + (size_t)b * PX;

    float4 p0 = *(const float4*)(pr + base);
    float4 p1 = *(const float4*)(pr + base + 4);
    int4   l0 = *(const int4*)(lb + base);
    int4   l1 = *(const int4*)(lb + base + 4);
    int4   m0 = *(const int4*)(mk + base);
    int4   m1 = *(const int4*)(mk + base + 4);

    float ps[8] = {p0.x, p0.y, p0.z, p0.w, p1.x, p1.y, p1.z, p1.w};
    float ls[8] = {(float)l0.x, (float)l0.y, (float)l0.z, (float)l0.w,
                   (float)l1.x, (float)l1.y, (float)l1.z, (float)l1.w};
    float ms[8] = {(float)m0.x, (float)m0.y, (float)m0.z, (float)m0.w,
                   (float)m1.x, (float)m1.y, (float)m1.z, (float)m1.w};

    unsigned pos = 0, nz = 0;
    float a0 = 0.f, a1 = 0.f, a2 = 0.f;
    unsigned long long wp = 0ull;
    #pragma unroll
    for (int u = 0; u < 8; u++) {
        float pn = sigf(ps[u]) * ms[u];
        bool P = (pn >= 0.5f);
        pos += P;
        nz  += (!P && __float_as_uint(pn) != 0u);
        wp  |= ((unsigned long long)(P ? 1u : 0u)) << (8 * u);
        float ln = ls[u] * ms[u];
        a0 += pn * ln;     // M == 1
        a1 += pn * pn;
        a2 += ln;          // ln*ln == ln (0/1)
    }
    *(unsigned long long*)(wmask + (size_t)b * PX + base) = wp;

    __shared__ float red[4][3];
    __shared__ unsigned ws2[2][4];
    int lane = threadIdx.x & 63, wid = threadIdx.x >> 6;
    float v0 = wred_f(a0), v1 = wred_f(a1), v2 = wred_f(a2);
    unsigned pv = wred_u(pos), zv = wred_u(nz);
    if (lane == 0) {
        red[wid][0] = v0; red[wid][1] = v1; red[wid][2] = v2;
        ws2[0][wid] = pv; ws2[1][wid] = zv;
    }
    __syncthreads();
    if (threadIdx.x < 3) {
        float tot = red[0][threadIdx.x] + red[1][threadIdx.x] +
                    red[2][threadIdx.x] + red[3][threadIdx.x];
        atomicAdd(&sums[((size_t)b * 7 + 6) * 3 + threadIdx.x], tot);
    }
    if (threadIdx.x == 64) {   // separate wave does the counter atomics
        unsigned pt = ws2[0][0] + ws2[0][1] + ws2[0][2] + ws2[0][3];
        unsigned zt = ws2[1][0] + ws2[1][1] + ws2[1][2] + ws2[1][3];
        if (pt) atomicAdd(&n_pos[b], pt);
        if (zt) atomicAdd(&n_nz[b], zt);
    }
}

// =====================================================================================
// K2: per-sample check. Fast path (this data, always): M == 1 -> k_prep's sums are
// already exact, return. Slow path (never taken, kept exact): 4-level LDS radix select
// for the k-th largest negative, then recompute the 3 L_c sums with Mi and overwrite.
// =====================================================================================
__global__ __launch_bounds__(256) void k_fix(const float* __restrict__ preds,
                                             const int* __restrict__ labels,
                                             const int* __restrict__ mask,
                                             const unsigned* __restrict__ n_pos,
                                             const unsigned* __restrict__ n_nz,
                                             float* __restrict__ sums) {
    int b = blockIdx.x;
    unsigned np_ = n_pos[b];
    unsigned k = np_ * 3u;
    unsigned nneg = (unsigned)PX - np_;
    bool active = (nneg > k) && (k > 0u);
    if (!active || k > n_nz[b]) return;   // M == 1: thr==0 (or inactive), sums exact

    // ---- slow path: exact k-th largest of uint bits over all negatives ----
    const float* pr = preds + ((size_t)b * NCH + 6) * PX;
    const int*   lb = labels + ((size_t)b * NCH + 6) * PX;
    const int*   mk = mask + (size_t)b * PX;
    __shared__ unsigned hist[256];
    __shared__ unsigned sh_sel, sh_rem;
    const unsigned masks[4] = {0x00000000u, 0xFF000000u, 0xFFFF0000u, 0xFFFFFF00u};
    unsigned prefix = 0u, krem = k;
    for (int lv = 0; lv < 4; lv++) {
        int shift = 24 - 8 * lv;
        unsigned msk = masks[lv];
        for (int j = threadIdx.x; j < 256; j += 256) hist[j] = 0u;
        __syncthreads();
        for (int g = threadIdx.x; g < PX / 4; g += 256) {
            int px = g * 4;
            float4 p4 = *(const float4*)(pr + px);
            int4   m4 = *(const int4*)(mk + px);
            float pa[4] = {p4.x, p4.y, p4.z, p4.w};
            float mm[4] = {(float)m4.x, (float)m4.y, (float)m4.z, (float)m4.w};
            #pragma unroll
            for (int u = 0; u < 4; u++) {
                float pn = sigf(pa[u]) * mm[u];
                if (pn < 0.5f) {
                    unsigned bits = __float_as_uint(pn);
                    if ((bits & msk) == prefix)
                        atomicAdd(&hist[(bits >> shift) & 0xFFu], 1u);
                }
            }
        }
        __syncthreads();
        if (threadIdx.x == 0) {
            unsigned acc = 0, rem = krem, sel = 0;
            for (int i = 255; i >= 0; i--) {
                acc += hist[i];
                if (acc >= krem) { sel = (unsigned)i; rem = krem - (acc - hist[i]); break; }
            }
            sh_sel = sel; sh_rem = rem;
        }
        __syncthreads();
        prefix |= (sh_sel << shift);
        krem = sh_rem;
        __syncthreads();
    }
    float thr = __uint_as_float(prefix);

    // recompute the 3 L_c sums with the Mi gate and overwrite
    float a0 = 0.f, a1 = 0.f, a2 = 0.f;
    for (int g = threadIdx.x; g < PX / 4; g += 256) {
        int px = g * 4;
        float4 p4 = *(const float4*)(pr + px);
        int4   l4 = *(const int4*)(lb + px);
        int4   m4 = *(const int4*)(mk + px);
        float pa[4] = {p4.x, p4.y, p4.z, p4.w};
        float la[4] = {(float)l4.x, (float)l4.y, (float)l4.z, (float)l4.w};
        float mm[4] = {(float)m4.x, (float)m4.y, (float)m4.z, (float)m4.w};
        #pragma unroll
        for (int u = 0; u < 4; u++) {
            float pn = sigf(pa[u]) * mm[u];
            float Mi = (pn >= thr) ? 1.0f : 0.0f;
            float ln = la[u] * mm[u];
            a0 += pn * ln * Mi;
            a1 += pn * pn * Mi;
            a2 += ln * Mi;
        }
    }
    __shared__ float red[4][3];
    int lane = threadIdx.x & 63, wid = threadIdx.x >> 6;
    float v0 = wred_f(a0), v1 = wred_f(a1), v2 = wred_f(a2);
    if (lane == 0) { red[wid][0] = v0; red[wid][1] = v1; red[wid][2] = v2; }
    __syncthreads();
    if (threadIdx.x < 3) {
        float tot = red[0][threadIdx.x] + red[1][threadIdx.x] +
                    red[2][threadIdx.x] + red[3][threadIdx.x];
        sums[((size_t)b * 7 + 6) * 3 + threadIdx.x] = tot;   // overwrite (stream-ordered)
    }
}

// =====================================================================================
// K3: ch 0..5 (157 MB). grid (PBLK, 6, BS), 8 px/thread straight-line, 5 load streams.
// =====================================================================================
__global__ __launch_bounds__(256, 4) void k_sums6(const float* __restrict__ preds,
                                                  const int* __restrict__ labels,
                                                  const unsigned char* __restrict__ wmask,
                                                  float* __restrict__ sums) {
    int b = blockIdx.z, ch = blockIdx.y;
    int base = (blockIdx.x * 256 + threadIdx.x) * 8;
    const float* pr = preds + ((size_t)b * NCH + ch) * PX;
    const int*   lb = labels + ((size_t)b * NCH + ch) * PX;

    float4 p0 = *(const float4*)(pr + base);
    float4 p1 = *(const float4*)(pr + base + 4);
    int4   l0 = *(const int4*)(lb + base);
    int4   l1 = *(const int4*)(lb + base + 4);
    unsigned long long wp = *(const unsigned long long*)(wmask + (size_t)b * PX + base);

    float ps[8] = {p0.x, p0.y, p0.z, p0.w, p1.x, p1.y, p1.z, p1.w};
    float ls[8] = {(float)l0.x, (float)l0.y, (float)l0.z, (float)l0.w,
                   (float)l1.x, (float)l1.y, (float)l1.z, (float)l1.w};

    float s0 = 0.f, s1 = 0.f, s2 = 0.f;
    #pragma unroll
    for (int u = 0; u < 8; u++) {
        float W = (float)((wp >> (8 * u)) & 1ull);
        float s = sigf(ps[u]);
        float l = ls[u];
        s0 += s * l * W;
        s1 += s * s * W;
        s2 += l * W;     // l*l == l (0/1)
    }

    __shared__ float red[4][3];
    int lane = threadIdx.x & 63, wid = threadIdx.x >> 6;
    float v0 = wred_f(s0), v1 = wred_f(s1), v2 = wred_f(s2);
    if (lane == 0) { red[wid][0] = v0; red[wid][1] = v1; red[wid][2] = v2; }
    __syncthreads();
    if (threadIdx.x < 3) {
        float tot = red[0][threadIdx.x] + red[1][threadIdx.x] +
                    red[2][threadIdx.x] + red[3][threadIdx.x];
        atomicAdd(&sums[((size_t)b * 7 + ch) * 3 + threadIdx.x], tot);
    }
}

// ---------------- K4: 168 floats -> dice -> 3 outputs -------------------------------
__global__ __launch_bounds__(256) void k_final(const float* __restrict__ sums,
                                               float* __restrict__ out) {
    __shared__ float fr[BS * 21];
    if (threadIdx.x < BS * 21) fr[threadIdx.x] = sums[threadIdx.x];
    __syncthreads();
    if (threadIdx.x == 0) {
        float Lc = 0.f, Ls = 0.f;
        #pragma unroll
        for (int b = 0; b < BS; b++) {
            const float* s6 = fr + (b * 7 + 6) * 3;
            Lc += 1.0f - (2.0f * s6[0]) / (s6[1] + s6[2] + EPSF);
            float acc = 0.f;
            #pragma unroll
            for (int c = 0; c < 6; c++) {
                const float* sc = fr + (b * 7 + c) * 3;
                acc += (2.0f * sc[0]) / (sc[1] + sc[2] + EPSF);
            }
            Ls += 1.0f - acc * (1.0f / 6.0f);
        }
        float lc_m = Lc * (1.0f / (float)BS);
        float ls_m = Ls * (1.0f / (float)BS);
        out[0] = lc_m;
        out[1] = ls_m;
        out[2] = 0.7f * lc_m + 0.3f * ls_m;
    }
}

extern "C" void kernel_launch(void* const* d_in, const int* in_sizes, int n_in,
                              void* d_out, int out_size, void* d_ws, size_t ws_size,
                              hipStream_t stream) {
    const float* preds = (const float*)d_in[0];
    const int* labels  = (const int*)d_in[1];
    const int* mask    = (const int*)d_in[2];
    float* out = (float*)d_out;

    // workspace layout: zeroed region first (184 words), then wmask
    unsigned* n_pos = (unsigned*)d_ws;                     // BS
    unsigned* n_nz  = n_pos + BS;                          // BS
    float*    sums  = (float*)(n_nz + BS);                 // BS*21
    unsigned char* wmask = (unsigned char*)(sums + BS * 21);  // BS*PX bytes (8B-aligned: 736%8==0)

    hipMemsetAsync(d_ws, 0, (2 * BS + BS * 21) * sizeof(unsigned), stream);

    hipLaunchKernelGGL(k_prep, dim3(PBLK, BS), dim3(256), 0, stream,
                       preds, labels, mask, n_pos, n_nz, wmask, sums);

    hipLaunchKernelGGL(k_fix, dim3(BS), dim3(256), 0, stream,
                       preds, labels, mask, n_pos, n_nz, sums);

    hipLaunchKernelGGL(k_sums6, dim3(PBLK, 6, BS), dim3(256), 0, stream,
                       preds, labels, wmask, sums);

    hipLaunchKernelGGL(k_final, dim3(1), dim3(256), 0, stream, sums, out);
}

// Round 6
// 237.522 us; speedup vs baseline: 2.1582x; 1.0796x over previous
//
#include <hip/hip_runtime.h>

#define BS   8
#define NCH  7
#define PX   409600      // 640*640
#define PBLK 400         // px-blocks per sample: 400*256*4 = PX
#define EPSF 1e-6f

// hardware reciprocal (v_rcp_f32, ~1ulp) — avoids the IEEE div sequence
__device__ __forceinline__ float sigf(float x) {
    return __builtin_amdgcn_rcpf(1.0f + __expf(-x));
}

__device__ __forceinline__ unsigned wred_u(unsigned v) {
    #pragma unroll
    for (int o = 32; o; o >>= 1) v += __shfl_down(v, o);
    return v;
}

__device__ __forceinline__ float wred_f(float v) {
    #pragma unroll
    for (int o = 32; o; o >>= 1) v += __shfl_down(v, o);
    return v;
}

// sums layout: sums[(b*7+ch)*3 + j]; ch 0..5 = L_s (sn,sp,sl), ch 6 = L_c (a0,a1,a2)

// =====================================================================================
// K1: THE single pass over all 196.6 MB. grid (PBLK, BS), 4 px/thread straight-line.
// All 15 load streams issued before any compute. W computed in-register (no wmask).
// L_c sums taken with M == 1 (exact fast path for this data; k_final repairs if not).
// Finish: 21 + 2 atomicAdds per block (~400 per address — proven cheap in R2/R5).
// =====================================================================================
__global__ __launch_bounds__(256, 4) void k_fat(const float* __restrict__ preds,
                                                const int* __restrict__ labels,
                                                const int* __restrict__ mask,
                                                unsigned* __restrict__ n_pos,
                                                unsigned* __restrict__ n_nz,
                                                float* __restrict__ sums) {
    int b = blockIdx.y;
    int base = (blockIdx.x * 256 + threadIdx.x) * 4;
    const float* pr = preds + (size_t)b * NCH * PX;
    const int*   lb = labels + (size_t)b * NCH * PX;
    const int*   mk = mask + (size_t)b * PX;

    // ---- issue ALL 15 vector loads up front ----
    int4   m4 = *(const int4*)(mk + base);
    float4 p[7];
    int4   l[7];
    #pragma unroll
    for (int c = 0; c < 7; c++) {
        p[c] = *(const float4*)(pr + c * PX + base);
        l[c] = *(const int4*)(lb + c * PX + base);
    }

    float ms[4] = {(float)m4.x, (float)m4.y, (float)m4.z, (float)m4.w};
    float p6[4] = {p[6].x, p[6].y, p[6].z, p[6].w};
    float l6[4] = {(float)l[6].x, (float)l[6].y, (float)l[6].z, (float)l[6].w};

    unsigned pos = 0, nz = 0;
    float a0 = 0.f, a1 = 0.f, a2 = 0.f;
    float W[4];
    #pragma unroll
    for (int u = 0; u < 4; u++) {
        float pn = sigf(p6[u]) * ms[u];
        bool P = (pn >= 0.5f);
        pos += P;
        nz  += (!P && __float_as_uint(pn) != 0u);
        W[u] = P ? 1.0f : 0.0f;
        float ln = l6[u] * ms[u];
        a0 += pn * ln;     // M == 1 fast path
        a1 += pn * pn;
        a2 += ln;          // ln*ln == ln (0/1)
    }

    float acc[18];
    #pragma unroll
    for (int j = 0; j < 18; j++) acc[j] = 0.f;
    #pragma unroll
    for (int c = 0; c < 6; c++) {
        float ps[4] = {p[c].x, p[c].y, p[c].z, p[c].w};
        float ls[4] = {(float)l[c].x, (float)l[c].y, (float)l[c].z, (float)l[c].w};
        #pragma unroll
        for (int u = 0; u < 4; u++) {
            float s = sigf(ps[u]);
            float lw = ls[u] * W[u];
            acc[c]      += s * lw;        // sn
            acc[6 + c]  += s * s * W[u];  // sp
            acc[12 + c] += lw;            // sl (l*l == l)
        }
    }

    // ---- block reduction: 21 floats + 2 uints ----
    __shared__ float red[4][21];
    __shared__ unsigned ws2[2][4];
    int lane = threadIdx.x & 63, wid = threadIdx.x >> 6;
    {
        float v = wred_f(a0); if (lane == 0) red[wid][18] = v;
        v = wred_f(a1);       if (lane == 0) red[wid][19] = v;
        v = wred_f(a2);       if (lane == 0) red[wid][20] = v;
    }
    #pragma unroll
    for (int j = 0; j < 18; j++) {
        float v = wred_f(acc[j]);
        if (lane == 0) red[wid][j] = v;
    }
    unsigned pv = wred_u(pos), zv = wred_u(nz);
    if (lane == 0) { ws2[0][wid] = pv; ws2[1][wid] = zv; }
    __syncthreads();
    if (threadIdx.x < 21) {
        float tot = red[0][threadIdx.x] + red[1][threadIdx.x] +
                    red[2][threadIdx.x] + red[3][threadIdx.x];
        // map: j<18 -> ch=j%... store as (b*7+ch)*3+k ; j>=18 -> ch6 slots
        int j = threadIdx.x;
        int idx = (j < 18) ? (((size_t)b * 7 + (j % 6)) * 3 + (j / 6))
                           : (((size_t)b * 7 + 6) * 3 + (j - 18));
        atomicAdd(&sums[idx], tot);
    }
    if (threadIdx.x == 64) {
        unsigned pt = ws2[0][0] + ws2[0][1] + ws2[0][2] + ws2[0][3];
        unsigned zt = ws2[1][0] + ws2[1][1] + ws2[1][2] + ws2[1][3];
        if (pt) atomicAdd(&n_pos[b], pt);
        if (zt) atomicAdd(&n_nz[b], zt);
    }
}

// =====================================================================================
// K2: single block. Per-sample OHEM check; fast path (always, for this data): M == 1,
// sums already exact. Slow path kept exact (4-level LDS radix select + recompute).
// Then dice + means -> 3 outputs.
// =====================================================================================
__global__ __launch_bounds__(256) void k_final(const float* __restrict__ preds,
                                               const int* __restrict__ labels,
                                               const int* __restrict__ mask,
                                               const unsigned* __restrict__ n_pos,
                                               const unsigned* __restrict__ n_nz,
                                               const float* __restrict__ sums,
                                               float* __restrict__ out) {
    __shared__ float fr[BS * 21];
    if (threadIdx.x < BS * 21) fr[threadIdx.x] = sums[threadIdx.x];
    __syncthreads();

    __shared__ unsigned hist[256];
    __shared__ unsigned sh_sel, sh_rem;
    __shared__ float red[4][3];

    for (int b = 0; b < BS; b++) {
        unsigned np_ = n_pos[b];
        unsigned k = np_ * 3u;
        unsigned nneg = (unsigned)PX - np_;
        bool active = (nneg > k) && (k > 0u);
        if (!active || k > n_nz[b]) continue;   // M == 1: fr already exact (uniform branch)

        // ---- slow path (never taken for this data, exact): radix select thr ----
        const float* pr = preds + ((size_t)b * NCH + 6) * PX;
        const int*   lb = labels + ((size_t)b * NCH + 6) * PX;
        const int*   mk = mask + (size_t)b * PX;
        unsigned prefix = 0u, krem = k;
        const unsigned masks[4] = {0x00000000u, 0xFF000000u, 0xFFFF0000u, 0xFFFFFF00u};
        for (int lv = 0; lv < 4; lv++) {
            int shift = 24 - 8 * lv;
            unsigned msk = masks[lv];
            hist[threadIdx.x] = 0u;
            __syncthreads();
            for (int g = threadIdx.x; g < PX / 4; g += 256) {
                int px = g * 4;
                float4 p4 = *(const float4*)(pr + px);
                int4   m4 = *(const int4*)(mk + px);
                float pa[4] = {p4.x, p4.y, p4.z, p4.w};
                float mm[4] = {(float)m4.x, (float)m4.y, (float)m4.z, (float)m4.w};
                #pragma unroll
                for (int u = 0; u < 4; u++) {
                    float pn = sigf(pa[u]) * mm[u];
                    if (pn < 0.5f) {
                        unsigned bits = __float_as_uint(pn);
                        if ((bits & msk) == prefix)
                            atomicAdd(&hist[(bits >> shift) & 0xFFu], 1u);
                    }
                }
            }
            __syncthreads();
            if (threadIdx.x == 0) {
                unsigned acc = 0, rem = krem, sel = 0;
                for (int i = 255; i >= 0; i--) {
                    acc += hist[i];
                    if (acc >= krem) { sel = (unsigned)i; rem = krem - (acc - hist[i]); break; }
                }
                sh_sel = sel; sh_rem = rem;
            }
            __syncthreads();
            prefix |= (sh_sel << shift);
            krem = sh_rem;
            __syncthreads();
        }
        float thr = __uint_as_float(prefix);

        float a0 = 0.f, a1 = 0.f, a2 = 0.f;
        for (int g = threadIdx.x; g < PX / 4; g += 256) {
            int px = g * 4;
            float4 p4 = *(const float4*)(pr + px);
            int4   l4 = *(const int4*)(lb + px);
            int4   m4 = *(const int4*)(mk + px);
            float pa[4] = {p4.x, p4.y, p4.z, p4.w};
            float la[4] = {(float)l4.x, (float)l4.y, (float)l4.z, (float)l4.w};
            float mm[4] = {(float)m4.x, (float)m4.y, (float)m4.z, (float)m4.w};
            #pragma unroll
            for (int u = 0; u < 4; u++) {
                float pn = sigf(pa[u]) * mm[u];
                float Mi = (pn >= thr) ? 1.0f : 0.0f;
                float ln = la[u] * mm[u];
                a0 += pn * ln * Mi;
                a1 += pn * pn * Mi;
                a2 += ln * Mi;
            }
        }
        int lane = threadIdx.x & 63, wid = threadIdx.x >> 6;
        float v0 = wred_f(a0), v1 = wred_f(a1), v2 = wred_f(a2);
        if (lane == 0) { red[wid][0] = v0; red[wid][1] = v1; red[wid][2] = v2; }
        __syncthreads();
        if (threadIdx.x < 3) {
            fr[(b * 7 + 6) * 3 + threadIdx.x] =
                red[0][threadIdx.x] + red[1][threadIdx.x] +
                red[2][threadIdx.x] + red[3][threadIdx.x];
        }
        __syncthreads();
    }

    if (threadIdx.x == 0) {
        float Lc = 0.f, Ls = 0.f;
        #pragma unroll
        for (int b = 0; b < BS; b++) {
            const float* s6 = fr + (b * 7 + 6) * 3;
            Lc += 1.0f - (2.0f * s6[0]) / (s6[1] + s6[2] + EPSF);
            float acc = 0.f;
            #pragma unroll
            for (int c = 0; c < 6; c++) {
                const float* sc = fr + (b * 7 + c) * 3;
                acc += (2.0f * sc[0]) / (sc[1] + sc[2] + EPSF);
            }
            Ls += 1.0f - acc * (1.0f / 6.0f);
        }
        float lc_m = Lc * (1.0f / (float)BS);
        float ls_m = Ls * (1.0f / (float)BS);
        out[0] = lc_m;
        out[1] = ls_m;
        out[2] = 0.7f * lc_m + 0.3f * ls_m;
    }
}

extern "C" void kernel_launch(void* const* d_in, const int* in_sizes, int n_in,
                              void* d_out, int out_size, void* d_ws, size_t ws_size,
                              hipStream_t stream) {
    const float* preds = (const float*)d_in[0];
    const int* labels  = (const int*)d_in[1];
    const int* mask    = (const int*)d_in[2];
    float* out = (float*)d_out;

    unsigned* n_pos = (unsigned*)d_ws;           // BS
    unsigned* n_nz  = n_pos + BS;                // BS
    float*    sums  = (float*)(n_nz + BS);       // BS*21

    hipMemsetAsync(d_ws, 0, (2 * BS + BS * 21) * sizeof(unsigned), stream);

    hipLaunchKernelGGL(k_fat, dim3(PBLK, BS), dim3(256), 0, stream,
                       preds, labels, mask, n_pos, n_nz, sums);

    hipLaunchKernelGGL(k_final, dim3(1), dim3(256), 0, stream,
                       preds, labels, mask, n_pos, n_nz, sums, out);
}